// Round 3
// baseline (1806.810 us; speedup 1.0000x reference)
//
#include <hip/hip_runtime.h>
#include <hip/hip_bf16.h>
#include <math.h>

#define NTOK 8192     // B*S
#define DMD  2048     // d_model
#define DCC  512      // d_cortical
#define TOKH 4194304  // NTOK*DCC
#define WSZ  262144   // DCC*DCC

typedef __attribute__((ext_vector_type(8))) short short8;
typedef __attribute__((ext_vector_type(4))) float f32x4;

// ---------------- helpers ---------------------------------------------------
__device__ inline float bf2f(unsigned short u) {
    union { unsigned int i; float f; } x; x.i = ((unsigned int)u) << 16; return x.f;
}
__device__ inline unsigned short f2bf(float f) {
    union { float f; unsigned int i; } x; x.f = f;
    unsigned int u = x.i;
    return (unsigned short)((u + 0x7fffu + ((u >> 16) & 1u)) >> 16);
}

// async global->LDS, 16B per lane; LDS dest is wave-uniform base + lane*16.
typedef const __attribute__((address_space(1))) unsigned int* gas1_t;
typedef __attribute__((address_space(3))) unsigned int* las3_t;
__device__ inline void async16(const void* g, void* l) {
    __builtin_amdgcn_global_load_lds(
        (gas1_t)g,
        (las3_t)(unsigned int)(unsigned long long)l, 16, 0, 0);
}

// ---------------- fp32 -> bf16 conversion (bulk activations) ----------------
__global__ __launch_bounds__(256)
void cvt_kernel(const float* __restrict__ s, unsigned short* __restrict__ d, int n4)
{
    int i = blockIdx.x * 256 + threadIdx.x;
    if (i >= n4) return;
    float4 v = ((const float4*)s)[i];
    ushort4 o;
    o.x = f2bf(v.x); o.y = f2bf(v.y); o.z = f2bf(v.z); o.w = f2bf(v.w);
    ((ushort4*)d)[i] = o;
}

// ---------------- merged fp32 -> bf16 weight conversion ---------------------
struct CvtArgs { const float* src[7]; };

__global__ __launch_bounds__(256)
void wcvt_kernel(CvtArgs ca, unsigned short* __restrict__ dst)
{
    const int total = 2359296;  // f4 units
    for (int i = blockIdx.x * 256 + threadIdx.x; i < total; i += gridDim.x * 256) {
        const float* sp; int base;
        if      (i < 1048576) { sp = ca.src[0]; base = 0;       }  // proj_W
        else if (i < 1310720) { sp = ca.src[1]; base = 1048576; }  // fuse_W
        else if (i < 1572864) { sp = ca.src[2]; base = 1310720; }  // up_W
        else if (i < 1835008) { sp = ca.src[3]; base = 1572864; }  // lateral_W
        else if (i < 2031616) { sp = ca.src[4]; base = 1835008; }  // down_W
        else if (i < 2097152) { sp = ca.src[5]; base = 2031616; }  // out1_W
        else                  { sp = ca.src[6]; base = 2097152; }  // out2_W
        float4 v = ((const float4*)sp)[i - base];
        ushort4 o;
        o.x = f2bf(v.x); o.y = f2bf(v.y); o.z = f2bf(v.z); o.w = f2bf(v.w);
        ((ushort4*)dst)[i] = o;
    }
}

// ---------------- batched bf16 MFMA GEMM (m97 structure + XCD swizzle) ------
struct GArgs {
    const unsigned short* A[6];
    const unsigned short* W[6];
    const float*          bias[6];
    const float*          add[6];
    void*                 C[6];
};

template<bool OUTF32, bool GELU>
__global__ __launch_bounds__(256)
void gemm16(GArgs ga, int lda, int ldw, int ldadd, int ldc, int K)
{
    __shared__ unsigned short As[128 * 32];   // 8 KB
    __shared__ unsigned short Bs[128 * 32];   // 8 KB

    const int z    = blockIdx.z;
    const int tid  = threadIdx.x;
    const int wave = tid >> 6;
    const int lane = tid & 63;

    // XCD-chunked bijective swizzle (nwg % 8 == 0)
    const int nwg   = gridDim.x * gridDim.y;
    const int bid   = blockIdx.y * gridDim.x + blockIdx.x;
    const int swz   = (bid & 7) * (nwg >> 3) + (bid >> 3);
    const int bn    = (swz % gridDim.x) * 128;
    const int bm    = (swz / gridDim.x) * 128;

    const int wr   = wave >> 1;
    const int wc   = wave & 1;

    const unsigned short* Ap = ga.A[z];
    const unsigned short* Wp = ga.W[z];

    const int lrow = lane >> 2;
    const int lcol = (lane & 3) * 8;

    f32x4 acc[4][4] = {};

    for (int k0 = 0; k0 < K; k0 += 32) {
        #pragma unroll
        for (int r = 0; r < 2; ++r) {
            int c = wave + r * 4;
            async16(Ap + (size_t)(bm + c * 16 + lrow) * lda + k0 + lcol, As + c * 512);
            async16(Wp + (size_t)(bn + c * 16 + lrow) * ldw + k0 + lcol, Bs + c * 512);
        }
        __syncthreads();

        short8 af[4], bfr[4];
        #pragma unroll
        for (int i = 0; i < 4; ++i) {
            af[i]  = *(const short8*)&As[(wr * 64 + i * 16 + (lane & 15)) * 32 + (lane >> 4) * 8];
            bfr[i] = *(const short8*)&Bs[(wc * 64 + i * 16 + (lane & 15)) * 32 + (lane >> 4) * 8];
        }
        #pragma unroll
        for (int mi = 0; mi < 4; ++mi)
            #pragma unroll
            for (int ni = 0; ni < 4; ++ni)
                acc[mi][ni] = __builtin_amdgcn_mfma_f32_16x16x32_bf16(
                    af[mi], bfr[ni], acc[mi][ni], 0, 0, 0);
        __syncthreads();
    }

    const float* bias = ga.bias[z];
    const float* add  = ga.add[z];
    #pragma unroll
    for (int ni = 0; ni < 4; ++ni) {
        int col = bn + wc * 64 + ni * 16 + (lane & 15);
        float bv = bias ? bias[col] : 0.0f;
        #pragma unroll
        for (int mi = 0; mi < 4; ++mi) {
            #pragma unroll
            for (int r = 0; r < 4; ++r) {
                int row = bm + wr * 64 + mi * 16 + (lane >> 4) * 4 + r;
                float vv = acc[mi][ni][r] + bv;
                if (GELU) vv = 0.5f * vv * (1.0f + erff(vv * 0.7071067811865475f));
                if (OUTF32) {
                    if (add) vv += add[(size_t)row * ldadd + col];
                    ((float*)ga.C[z])[(size_t)row * ldc + col] = vv;
                } else {
                    ((unsigned short*)ga.C[z])[(size_t)row * ldc + col] = f2bf(vv);
                }
            }
        }
    }
}

// ---------------- fused layer kernel ----------------------------------------
// Block: 32 rows x 512 cols, K=512, 4 waves (wave w owns cols w*128..+127).
// SETTLE=0: out = LN(A@upW^T + up_b); APPEND=1 also writes ap_out = out@apW^T+ap_b
// SETTLE=1: lat  = a_in@latW^T + lat_b           (pre-update acts[i])
//           comp = LN1(A@upW^T + up_b)
//           tgt  = TGTG ? t_in : a_in
//           out  = LN2(a_in + 0.5*(comp-tgt)*sigmoid(logit) + 0.1*lat)
//           APPEND=1: ap_out = out@apW^T + ap_b  (pred for next iter)
//           APPEND=2: ap_out = gelu(out@apW^T + ap_b)  (head out1)
// LDS: Bs dbuf 64K + As 4K + compS 32K + latS 32K + red 1K = 133 KB.
__device__ inline int csw(int rl, int col) {
    int s = ((rl >> 2) & 3) ^ (rl & 3);
    return rl * 512 + (col ^ (s << 4));
}

template<bool SETTLE, bool TGTG, int APPEND>
__global__ __launch_bounds__(256)
void gemm_fused(const unsigned short* __restrict__ Ap,
                const unsigned short* __restrict__ upW,
                const float* __restrict__ up_bias,
                const float* __restrict__ g,
                const float* __restrict__ b,
                const unsigned short* a_in,
                const unsigned short* t_in,
                const unsigned short* __restrict__ latW,
                const float* __restrict__ lat_bias,
                const float* __restrict__ logit,
                unsigned short* outp,
                const unsigned short* __restrict__ apW,
                const float* __restrict__ ap_bias,
                unsigned short* ap_out)
{
    __shared__ unsigned short Bs[2][512 * 32];   // 64 KB dbuf
    __shared__ unsigned short As2[2][32 * 32];   //  4 KB dbuf
    __shared__ unsigned short compS[32 * 512];   // 32 KB
    __shared__ unsigned short latS[32 * 512];    // 32 KB
    __shared__ float red[2][4][32];              //  1 KB

    const int tid  = threadIdx.x;
    const int wave = tid >> 6;
    const int lane = tid & 63;
    const int lrow = lane >> 2;
    const int lc8  = (lane & 3) * 8;
    const int bm   = blockIdx.x * 32;
    const int l15  = lane & 15;
    const int lh   = lane >> 4;

    f32x4 acc[2][8];

    auto run = [&](const unsigned short* Ag, const unsigned short* Wg) {
        #pragma unroll
        for (int mi = 0; mi < 2; ++mi)
            #pragma unroll
            for (int ni = 0; ni < 8; ++ni)
                acc[mi][ni] = f32x4{0.f, 0.f, 0.f, 0.f};
        if (wave < 2)
            async16(Ag + (size_t)(bm + wave * 16 + lrow) * DCC + lc8, &As2[0][wave * 512]);
        #pragma unroll
        for (int r = 0; r < 8; ++r)
            async16(Wg + (size_t)((r * 4 + wave) * 16 + lrow) * DCC + lc8,
                    &Bs[0][(r * 4 + wave) * 512]);
        __syncthreads();
        for (int t = 0; t < 16; ++t) {
            const int cur = t & 1;
            if (t < 15) {
                const int k0 = (t + 1) * 32;
                if (wave < 2)
                    async16(Ag + (size_t)(bm + wave * 16 + lrow) * DCC + k0 + lc8,
                            &As2[cur ^ 1][wave * 512]);
                #pragma unroll
                for (int r = 0; r < 8; ++r)
                    async16(Wg + (size_t)((r * 4 + wave) * 16 + lrow) * DCC + k0 + lc8,
                            &Bs[cur ^ 1][(r * 4 + wave) * 512]);
            }
            short8 af[2];
            #pragma unroll
            for (int mi = 0; mi < 2; ++mi)
                af[mi] = *(const short8*)&As2[cur][(mi * 16 + l15) * 32 + lh * 8];
            #pragma unroll
            for (int ni = 0; ni < 8; ++ni) {
                short8 bf8 = *(const short8*)&Bs[cur][(wave * 128 + ni * 16 + l15) * 32 + lh * 8];
                #pragma unroll
                for (int mi = 0; mi < 2; ++mi)
                    acc[mi][ni] = __builtin_amdgcn_mfma_f32_16x16x32_bf16(
                        af[mi], bf8, acc[mi][ni], 0, 0, 0);
            }
            __syncthreads();
        }
    };

    // ---- lateral GEMM first (pre-update acts[i]); stage to latS -------------
    if constexpr (SETTLE) {
        run(a_in, latW);
        #pragma unroll
        for (int ni = 0; ni < 8; ++ni) {
            int col = wave * 128 + ni * 16 + l15;
            float lb = lat_bias[col];
            #pragma unroll
            for (int mi = 0; mi < 2; ++mi)
                #pragma unroll
                for (int rr = 0; rr < 4; ++rr)
                    latS[csw(mi * 16 + lh * 4 + rr, col)] = f2bf(acc[mi][ni][rr] + lb);
        }
        // up-run's prologue barrier orders these writes before any read
    }

    // ---- up GEMM ------------------------------------------------------------
    run(Ap, upW);

    // ---- LN1 row stats in MFMA layout ---------------------------------------
    float bv[8], gv[8], bbv[8];
    #pragma unroll
    for (int ni = 0; ni < 8; ++ni) {
        int col = wave * 128 + ni * 16 + l15;
        bv[ni] = up_bias[col]; gv[ni] = g[col]; bbv[ni] = b[col];
    }

    float ps[2][4], pq[2][4];
    #pragma unroll
    for (int mi = 0; mi < 2; ++mi)
        #pragma unroll
        for (int rr = 0; rr < 4; ++rr) {
            float s = 0.f, q = 0.f;
            #pragma unroll
            for (int ni = 0; ni < 8; ++ni) {
                float v = acc[mi][ni][rr] + bv[ni];
                acc[mi][ni][rr] = v;
                s += v; q += v * v;
            }
            #pragma unroll
            for (int off = 1; off < 16; off <<= 1) {
                s += __shfl_xor(s, off, 64);
                q += __shfl_xor(q, off, 64);
            }
            ps[mi][rr] = s; pq[mi][rr] = q;
        }
    if (l15 == 0) {
        #pragma unroll
        for (int mi = 0; mi < 2; ++mi)
            #pragma unroll
            for (int rr = 0; rr < 4; ++rr) {
                int rl = mi * 16 + lh * 4 + rr;
                red[0][wave][rl] = ps[mi][rr];
                red[1][wave][rl] = pq[mi][rr];
            }
    }
    __syncthreads();

    // comp = LN1 result -> compS
    #pragma unroll
    for (int mi = 0; mi < 2; ++mi)
        #pragma unroll
        for (int rr = 0; rr < 4; ++rr) {
            int rl = mi * 16 + lh * 4 + rr;
            float s = red[0][0][rl] + red[0][1][rl] + red[0][2][rl] + red[0][3][rl];
            float q = red[1][0][rl] + red[1][1][rl] + red[1][2][rl] + red[1][3][rl];
            float m1 = s * (1.0f / DCC);
            float r1 = rsqrtf(q * (1.0f / DCC) - m1 * m1 + 1e-5f);
            #pragma unroll
            for (int ni = 0; ni < 8; ++ni) {
                int col = wave * 128 + ni * 16 + l15;
                compS[csw(rl, col)] = f2bf((acc[mi][ni][rr] - m1) * r1 * gv[ni] + bbv[ni]);
            }
        }
    __syncthreads();

    // ---- phase 2: row-mapped (wave owns 8 rows, lane owns 8 contiguous cols)
    const int c0 = lane * 8;
    if constexpr (!SETTLE) {
        #pragma unroll
        for (int rr = 0; rr < 8; ++rr) {
            const int rl = wave * 8 + rr;
            const size_t gbase = (size_t)(bm + rl) * DCC + c0;
            short8 cm = *(const short8*)&compS[csw(rl, c0)];
            *(short8*)(outp + gbase) = cm;
        }
    } else {
        float gr[8], br[8], pr[8];
        {
            float4 g0 = *(const float4*)(g + c0),     g1 = *(const float4*)(g + c0 + 4);
            float4 b0 = *(const float4*)(b + c0),     b1 = *(const float4*)(b + c0 + 4);
            float4 p0 = *(const float4*)(logit + c0), p1 = *(const float4*)(logit + c0 + 4);
            float gt[8] = {g0.x,g0.y,g0.z,g0.w,g1.x,g1.y,g1.z,g1.w};
            float bt[8] = {b0.x,b0.y,b0.z,b0.w,b1.x,b1.y,b1.z,b1.w};
            float pt[8] = {p0.x,p0.y,p0.z,p0.w,p1.x,p1.y,p1.z,p1.w};
            #pragma unroll
            for (int j = 0; j < 8; ++j) {
                gr[j] = gt[j]; br[j] = bt[j];
                pr[j] = 1.0f / (1.0f + __expf(-pt[j]));
            }
        }
        #pragma unroll
        for (int rr = 0; rr < 8; ++rr) {
            const int rl = wave * 8 + rr;
            const size_t gbase = (size_t)(bm + rl) * DCC + c0;
            short8 cm = *(const short8*)&compS[csw(rl, c0)];
            short8 lm = *(const short8*)&latS[csw(rl, c0)];
            short8 ar = *(const short8*)(a_in + gbase);
            short8 tr;
            if constexpr (TGTG) tr = *(const short8*)(t_in + gbase);
            else                tr = ar;
            float tv[8], s = 0.f, q = 0.f;
            #pragma unroll
            for (int j = 0; j < 8; ++j) {
                float val = bf2f((unsigned short)ar[j])
                          + 0.5f * (bf2f((unsigned short)cm[j]) - bf2f((unsigned short)tr[j])) * pr[j]
                          + 0.1f * bf2f((unsigned short)lm[j]);
                tv[j] = val; s += val; q += val * val;
            }
            #pragma unroll
            for (int off = 1; off < 64; off <<= 1) {
                s += __shfl_xor(s, off, 64);
                q += __shfl_xor(q, off, 64);
            }
            float m2 = s * (1.0f / DCC);
            float r2 = rsqrtf(q * (1.0f / DCC) - m2 * m2 + 1e-5f);
            short8 o;
            #pragma unroll
            for (int j = 0; j < 8; ++j)
                o[j] = (short)f2bf((tv[j] - m2) * r2 * gr[j] + br[j]);
            *(short8*)(outp + gbase) = o;
            if constexpr (APPEND > 0)
                *(short8*)&compS[csw(rl, c0)] = o;   // new acts for append GEMM
        }
    }

    // ---- appended GEMM: ap_out = f(out @ apW^T + ap_b), A read from compS ---
    if constexpr (APPEND > 0) {
        __syncthreads();
        #pragma unroll
        for (int mi = 0; mi < 2; ++mi)
            #pragma unroll
            for (int ni = 0; ni < 8; ++ni)
                acc[mi][ni] = f32x4{0.f, 0.f, 0.f, 0.f};
        #pragma unroll
        for (int r = 0; r < 8; ++r)
            async16(apW + (size_t)((r * 4 + wave) * 16 + lrow) * DCC + lc8,
                    &Bs[0][(r * 4 + wave) * 512]);
        __syncthreads();
        for (int t = 0; t < 16; ++t) {
            const int cur = t & 1;
            if (t < 15) {
                const int k0 = (t + 1) * 32;
                #pragma unroll
                for (int r = 0; r < 8; ++r)
                    async16(apW + (size_t)((r * 4 + wave) * 16 + lrow) * DCC + k0 + lc8,
                            &Bs[cur ^ 1][(r * 4 + wave) * 512]);
            }
            short8 af[2];
            #pragma unroll
            for (int mi = 0; mi < 2; ++mi)
                af[mi] = *(const short8*)&compS[csw(mi * 16 + l15, t * 32 + lh * 8)];
            #pragma unroll
            for (int ni = 0; ni < 8; ++ni) {
                short8 bf8 = *(const short8*)&Bs[cur][(wave * 128 + ni * 16 + l15) * 32 + lh * 8];
                #pragma unroll
                for (int mi = 0; mi < 2; ++mi)
                    acc[mi][ni] = __builtin_amdgcn_mfma_f32_16x16x32_bf16(
                        af[mi], bf8, acc[mi][ni], 0, 0, 0);
            }
            __syncthreads();
        }
        #pragma unroll
        for (int ni = 0; ni < 8; ++ni) {
            int col = wave * 128 + ni * 16 + l15;
            float ab = ap_bias[col];
            #pragma unroll
            for (int mi = 0; mi < 2; ++mi)
                #pragma unroll
                for (int rr = 0; rr < 4; ++rr) {
                    int row = bm + mi * 16 + lh * 4 + rr;
                    float vv = acc[mi][ni][rr] + ab;
                    if (APPEND == 2)
                        vv = 0.5f * vv * (1.0f + erff(vv * 0.7071067811865475f));
                    ap_out[(size_t)row * DCC + col] = f2bf(vv);
                }
        }
    }
}

// ---------------------------------------------------------------------------
extern "C" void kernel_launch(void* const* d_in, const int* in_sizes, int n_in,
                              void* d_out, int out_size, void* d_ws, size_t ws_size,
                              hipStream_t stream)
{
    const float* qwen   = (const float*)d_in[0];
    const float* obs    = (const float*)d_in[1];
    const float* proj_W = (const float*)d_in[2];
    const float* proj_b = (const float*)d_in[3];
    const float* fuse_W = (const float*)d_in[4];
    const float* fuse_b = (const float*)d_in[5];
    const float* up_W   = (const float*)d_in[6];
    const float* up_b   = (const float*)d_in[7];
    const float* lat_W  = (const float*)d_in[8];
    const float* lat_b  = (const float*)d_in[9];
    const float* plogit = (const float*)d_in[10];
    const float* ln_g   = (const float*)d_in[11];
    const float* ln_b   = (const float*)d_in[12];
    const float* down_W = (const float*)d_in[13];
    const float* down_b = (const float*)d_in[14];
    const float* out1_W = (const float*)d_in[15];
    const float* out1_b = (const float*)d_in[16];
    const float* out2_W = (const float*)d_in[17];
    const float* out2_b = (const float*)d_in[18];
    float* out = (float*)d_out;

    // ---- ws layout (ushort): cat | x0 | acts0..3 | weights | obs16
    unsigned short* wsu = (unsigned short*)d_ws;
    unsigned short* catbuf = wsu;                          // 16,777,216
    unsigned short* x0b    = wsu + 16777216;               // 4,194,304
    unsigned short* acts16[4] = {
        wsu + 20971520, wsu + 20971520 + TOKH,
        wsu + 20971520 + 2 * TOKH, wsu + 20971520 + 3 * TOKH };
    unsigned short* w16    = wsu + 37748736;               // 9,437,184
    unsigned short* projW16 = w16;                         // 4,194,304
    unsigned short* fuseW16 = w16 + 4194304;               // 1,048,576
    unsigned short* upW16   = w16 + 5242880;               // 1,048,576
    unsigned short* latW16  = w16 + 6291456;               // 1,048,576
    unsigned short* downW16 = w16 + 7340032;               //   786,432
    unsigned short* out1W16 = w16 + 8126464;               //   262,144
    unsigned short* out2W16 = w16 + 8388608;               // 1,048,576
    unsigned short* obs16   = wsu + 47185920;              // 67,108,864 (134 MB)
    unsigned short* h16     = catbuf;                      // alias (cat dead after fuse)

    // ---- d_out overlays (pred a/b; dead before final out2 GEMM rewrites out)
    unsigned short* outu = (unsigned short*)d_out;
    unsigned short* pred16a = outu;
    unsigned short* pred16b = outu + TOKH;

    dim3 blk(256);

    // ---- all weight conversions in one launch
    {
        CvtArgs ca;
        ca.src[0] = proj_W; ca.src[1] = fuse_W; ca.src[2] = up_W;
        ca.src[3] = lat_W;  ca.src[4] = down_W; ca.src[5] = out1_W;
        ca.src[6] = out2_W;
        wcvt_kernel<<<dim3(2048), blk, 0, stream>>>(ca, w16);
    }

    // ---- full obs -> bf16 (one launch), then proj z=4 GEMM into cat cols
    {
        int n4 = (4 * NTOK * DMD) / 4;
        cvt_kernel<<<dim3(n4 / 256), blk, 0, stream>>>(obs, obs16, n4);
        GArgs a{};
        for (int o = 0; o < 4; ++o) {
            a.A[o]    = obs16 + (size_t)o * NTOK * DMD;
            a.W[o]    = projW16 + (size_t)o * DCC * DMD;
            a.bias[o] = proj_b + o * DCC;
            a.C[o]    = catbuf + o * DCC;        // ldc = 2048, column offset
        }
        gemm16<false, false><<<dim3(DCC/128, NTOK/128, 4), blk, 0, stream>>>(
            a, DMD, DMD, 0, 4 * DCC, DMD);
    }
    // ---- fuse: x0 = cat @ fuse_W^T + fuse_b  (K=2048)
    {
        GArgs a{};
        a.A[0] = catbuf; a.W[0] = fuseW16; a.bias[0] = fuse_b; a.C[0] = x0b;
        gemm16<false, false><<<dim3(DCC/128, NTOK/128, 1), blk, 0, stream>>>(
            a, 4 * DCC, 4 * DCC, 0, DCC, 4 * DCC);
    }

    dim3 fgrid(NTOK / 32);

    // ---- initial bottom-up pass; L1/L2 also seed preds for settle iter 0
    gemm_fused<false, false, 0><<<fgrid, blk, 0, stream>>>(
        x0b, upW16, up_b, ln_g, ln_b,
        nullptr, nullptr, nullptr, nullptr, nullptr, acts16[0],
        nullptr, nullptr, nullptr);
    gemm_fused<false, false, 1><<<fgrid, blk, 0, stream>>>(
        acts16[0], upW16 + WSZ, up_b + DCC, ln_g + DCC, ln_b + DCC,
        nullptr, nullptr, nullptr, nullptr, nullptr, acts16[1],
        downW16 + WSZ, down_b + DCC, pred16a);
    gemm_fused<false, false, 1><<<fgrid, blk, 0, stream>>>(
        acts16[1], upW16 + 2 * WSZ, up_b + 2 * DCC, ln_g + 2 * DCC, ln_b + 2 * DCC,
        nullptr, nullptr, nullptr, nullptr, nullptr, acts16[2],
        downW16 + 2 * WSZ, down_b + 2 * DCC, pred16b);
    gemm_fused<false, false, 0><<<fgrid, blk, 0, stream>>>(
        acts16[2], upW16 + 3 * WSZ, up_b + 3 * DCC, ln_g + 3 * DCC, ln_b + 3 * DCC,
        nullptr, nullptr, nullptr, nullptr, nullptr, acts16[3],
        nullptr, nullptr, nullptr);

    // ---- settling iterations (lat fused in; preds produced by L1/L2 appends)
    for (int s = 0; s < 5; ++s) {
        // L0: tgt = pred16a
        gemm_fused<true, true, 0><<<fgrid, blk, 0, stream>>>(
            x0b, upW16, up_b, ln_g, ln_b,
            acts16[0], pred16a, latW16, lat_b, plogit, acts16[0],
            nullptr, nullptr, nullptr);
        // L1: tgt = pred16b; append pred16a for next iter (skip on last)
        if (s < 4)
            gemm_fused<true, true, 1><<<fgrid, blk, 0, stream>>>(
                acts16[0], upW16 + WSZ, up_b + DCC, ln_g + DCC, ln_b + DCC,
                acts16[1], pred16b, latW16 + WSZ, lat_b + DCC, plogit + DCC, acts16[1],
                downW16 + WSZ, down_b + DCC, pred16a);
        else
            gemm_fused<true, true, 0><<<fgrid, blk, 0, stream>>>(
                acts16[0], upW16 + WSZ, up_b + DCC, ln_g + DCC, ln_b + DCC,
                acts16[1], pred16b, latW16 + WSZ, lat_b + DCC, plogit + DCC, acts16[1],
                nullptr, nullptr, nullptr);
        // L2: tgt = self; append pred16b for next iter (skip on last)
        if (s < 4)
            gemm_fused<true, false, 1><<<fgrid, blk, 0, stream>>>(
                acts16[1], upW16 + 2 * WSZ, up_b + 2 * DCC, ln_g + 2 * DCC, ln_b + 2 * DCC,
                acts16[2], nullptr, latW16 + 2 * WSZ, lat_b + 2 * DCC, plogit + 2 * DCC, acts16[2],
                downW16 + 2 * WSZ, down_b + 2 * DCC, pred16b);
        else
            gemm_fused<true, false, 0><<<fgrid, blk, 0, stream>>>(
                acts16[1], upW16 + 2 * WSZ, up_b + 2 * DCC, ln_g + 2 * DCC, ln_b + 2 * DCC,
                acts16[2], nullptr, latW16 + 2 * WSZ, lat_b + 2 * DCC, plogit + 2 * DCC, acts16[2],
                nullptr, nullptr, nullptr);
        // L3: tgt = self; on last iter append h = gelu(acts3 @ out1W + b)
        if (s < 4)
            gemm_fused<true, false, 0><<<fgrid, blk, 0, stream>>>(
                acts16[2], upW16 + 3 * WSZ, up_b + 3 * DCC, ln_g + 3 * DCC, ln_b + 3 * DCC,
                acts16[3], nullptr, latW16 + 3 * WSZ, lat_b + 3 * DCC, plogit + 3 * DCC, acts16[3],
                nullptr, nullptr, nullptr);
        else
            gemm_fused<true, false, 2><<<fgrid, blk, 0, stream>>>(
                acts16[2], upW16 + 3 * WSZ, up_b + 3 * DCC, ln_g + 3 * DCC, ln_b + 3 * DCC,
                acts16[3], nullptr, latW16 + 3 * WSZ, lat_b + 3 * DCC, plogit + 3 * DCC, acts16[3],
                out1W16, out1_b, h16);
    }

    // ---- head: out = qwen + h @ out2W^T + out2_b
    {
        GArgs a{};
        a.A[0] = h16; a.W[0] = out2W16; a.bias[0] = out2_b;
        a.add[0] = qwen; a.C[0] = out;
        gemm16<true, false><<<dim3(DMD/128, NTOK/128, 1), blk, 0, stream>>>(
            a, DCC, DCC, DMD, DMD, DCC);
    }
}

// Round 4
// 1574.299 us; speedup vs baseline: 1.1477x; 1.1477x over previous
//
#include <hip/hip_runtime.h>
#include <hip/hip_bf16.h>
#include <math.h>

#define NTOK 8192     // B*S
#define DMD  2048     // d_model
#define DCC  512      // d_cortical
#define TOKH 4194304  // NTOK*DCC

typedef __attribute__((ext_vector_type(8))) short short8;
typedef __attribute__((ext_vector_type(4))) float f32x4;

// ---------------- helpers ---------------------------------------------------
__device__ inline float bf2f(unsigned short u) {
    union { unsigned int i; float f; } x; x.i = ((unsigned int)u) << 16; return x.f;
}
__device__ inline unsigned short f2bf(float f) {
    union { float f; unsigned int i; } x; x.f = f;
    unsigned int u = x.i;
    return (unsigned short)((u + 0x7fffu + ((u >> 16) & 1u)) >> 16);
}

// async global->LDS, 16B per lane; LDS dest is wave-uniform base + lane*16.
typedef const __attribute__((address_space(1))) unsigned int* gas1_t;
typedef __attribute__((address_space(3))) unsigned int* las3_t;
__device__ inline void async16(const void* g, void* l) {
    __builtin_amdgcn_global_load_lds(
        (gas1_t)g,
        (las3_t)(unsigned int)(unsigned long long)l, 16, 0, 0);
}

// ---------------- fp32 -> bf16 conversion (bulk activations) ----------------
__global__ __launch_bounds__(256)
void cvt_kernel(const float* __restrict__ s, unsigned short* __restrict__ d, int n4)
{
    int i = blockIdx.x * 256 + threadIdx.x;
    if (i >= n4) return;
    float4 v = ((const float4*)s)[i];
    ushort4 o;
    o.x = f2bf(v.x); o.y = f2bf(v.y); o.z = f2bf(v.z); o.w = f2bf(v.w);
    ((ushort4*)d)[i] = o;
}

// ---------------- merged fp32 -> bf16 weight conversion ---------------------
struct CvtArgs { const float* src[7]; };

__global__ __launch_bounds__(256)
void wcvt_kernel(CvtArgs ca, unsigned short* __restrict__ dst)
{
    const int total = 2359296;  // f4 units
    for (int i = blockIdx.x * 256 + threadIdx.x; i < total; i += gridDim.x * 256) {
        const float* sp; int base;
        if      (i < 1048576) { sp = ca.src[0]; base = 0;       }  // proj_W
        else if (i < 1310720) { sp = ca.src[1]; base = 1048576; }  // fuse_W
        else if (i < 1572864) { sp = ca.src[2]; base = 1310720; }  // up_W
        else if (i < 1835008) { sp = ca.src[3]; base = 1572864; }  // lateral_W
        else if (i < 2031616) { sp = ca.src[4]; base = 1835008; }  // down_W
        else if (i < 2097152) { sp = ca.src[5]; base = 2031616; }  // out1_W
        else                  { sp = ca.src[6]; base = 2097152; }  // out2_W
        float4 v = ((const float4*)sp)[i - base];
        ushort4 o;
        o.x = f2bf(v.x); o.y = f2bf(v.y); o.z = f2bf(v.z); o.w = f2bf(v.w);
        ((ushort4*)dst)[i] = o;
    }
}

// ---------------- batched bf16 MFMA GEMM (m97 structure + XCD swizzle) ------
struct GArgs {
    const unsigned short* A[6];
    const unsigned short* W[6];
    const float*          bias[6];
    const float*          add[6];
    void*                 C[6];
};

template<bool OUTF32, bool GELU>
__global__ __launch_bounds__(256)
void gemm16(GArgs ga, int lda, int ldw, int ldadd, int ldc, int K)
{
    __shared__ unsigned short As[128 * 32];   // 8 KB
    __shared__ unsigned short Bs[128 * 32];   // 8 KB

    const int z    = blockIdx.z;
    const int tid  = threadIdx.x;
    const int wave = tid >> 6;
    const int lane = tid & 63;

    // XCD-chunked bijective swizzle (nwg % 8 == 0)
    const int nwg   = gridDim.x * gridDim.y;
    const int bid   = blockIdx.y * gridDim.x + blockIdx.x;
    const int swz   = (bid & 7) * (nwg >> 3) + (bid >> 3);
    const int bn    = (swz % gridDim.x) * 128;
    const int bm    = (swz / gridDim.x) * 128;

    const int wr   = wave >> 1;
    const int wc   = wave & 1;

    const unsigned short* Ap = ga.A[z];
    const unsigned short* Wp = ga.W[z];

    const int lrow = lane >> 2;
    const int lcol = (lane & 3) * 8;

    f32x4 acc[4][4] = {};

    for (int k0 = 0; k0 < K; k0 += 32) {
        #pragma unroll
        for (int r = 0; r < 2; ++r) {
            int c = wave + r * 4;
            async16(Ap + (size_t)(bm + c * 16 + lrow) * lda + k0 + lcol, As + c * 512);
            async16(Wp + (size_t)(bn + c * 16 + lrow) * ldw + k0 + lcol, Bs + c * 512);
        }
        __syncthreads();

        short8 af[4], bfr[4];
        #pragma unroll
        for (int i = 0; i < 4; ++i) {
            af[i]  = *(const short8*)&As[(wr * 64 + i * 16 + (lane & 15)) * 32 + (lane >> 4) * 8];
            bfr[i] = *(const short8*)&Bs[(wc * 64 + i * 16 + (lane & 15)) * 32 + (lane >> 4) * 8];
        }
        #pragma unroll
        for (int mi = 0; mi < 4; ++mi)
            #pragma unroll
            for (int ni = 0; ni < 4; ++ni)
                acc[mi][ni] = __builtin_amdgcn_mfma_f32_16x16x32_bf16(
                    af[mi], bfr[ni], acc[mi][ni], 0, 0, 0);
        __syncthreads();
    }

    const float* bias = ga.bias[z];
    const float* add  = ga.add[z];
    #pragma unroll
    for (int ni = 0; ni < 4; ++ni) {
        int col = bn + wc * 64 + ni * 16 + (lane & 15);
        float bv = bias ? bias[col] : 0.0f;
        #pragma unroll
        for (int mi = 0; mi < 4; ++mi) {
            #pragma unroll
            for (int r = 0; r < 4; ++r) {
                int row = bm + wr * 64 + mi * 16 + (lane >> 4) * 4 + r;
                float vv = acc[mi][ni][r] + bv;
                if (GELU) vv = 0.5f * vv * (1.0f + erff(vv * 0.7071067811865475f));
                if (OUTF32) {
                    if (add) vv += add[(size_t)row * ldadd + col];
                    ((float*)ga.C[z])[(size_t)row * ldc + col] = vv;
                } else {
                    ((unsigned short*)ga.C[z])[(size_t)row * ldc + col] = f2bf(vv);
                }
            }
        }
    }
}

// ---------------- fused GEMM + LN (+update), 8-wave version -----------------
// Block tile: 32 rows x 512 cols, K=512, 512 threads / 8 waves.
// Wave w owns output cols w*64..w*64+63 (acc[2][4]); 2 waves/SIMD for latency
// hiding (the R2 4-wave version ran at 1 wave/SIMD and was latency-bound).
// MODE 0: out = LN(A@W^T + bias)
// MODE 1: comp = LN1(A@W^T + bias);
//         out  = LN2(a_in + 0.5*(comp - tgt)*sigmoid(logit) + 0.1*lat)
// LDS: Bs dbuf 64K + As 4K + red 2K = 70 KB (compS reuses Bs[0]).
__device__ inline int csw(int rl, int col) {
    int s = ((rl >> 2) & 3) ^ (rl & 3);
    return rl * 512 + (col ^ (s << 4));
}

template<int MODE>
__global__ __launch_bounds__(512)
void gemm_fused(const unsigned short* __restrict__ Ap,
                const unsigned short* __restrict__ Wp,
                const float* __restrict__ bias,
                const float* __restrict__ g,
                const float* __restrict__ b,
                const unsigned short* a_in,
                const unsigned short* t_in,
                const unsigned short* __restrict__ lat_in,
                const float* __restrict__ logit,
                unsigned short* outp)
{
    __shared__ unsigned short Bs[2][512 * 32];   // 64 KB dbuf
    __shared__ unsigned short As2[2][32 * 32];   //  4 KB dbuf
    __shared__ float red[2][8][32];              //  2 KB

    const int tid  = threadIdx.x;
    const int wave = tid >> 6;         // 0..7
    const int lane = tid & 63;
    const int lrow = lane >> 2;        // 0..15
    const int lc8  = (lane & 3) * 8;   // 0,8,16,24
    const int bm   = blockIdx.x * 32;
    const int l15  = lane & 15;
    const int lh   = lane >> 4;

    f32x4 acc[2][4] = {};

    // prologue stage buf0, k=0
    if (wave < 2)
        async16(Ap + (size_t)(bm + wave * 16 + lrow) * DCC + lc8, &As2[0][wave * 512]);
    #pragma unroll
    for (int r = 0; r < 4; ++r)
        async16(Wp + (size_t)((r * 8 + wave) * 16 + lrow) * DCC + lc8,
                &Bs[0][(r * 8 + wave) * 512]);
    __syncthreads();   // drains vmcnt(0) -> buf0 ready

    for (int t = 0; t < 16; ++t) {
        const int cur = t & 1;
        if (t < 15) {  // prefetch next K-tile into other buffer
            const int k0 = (t + 1) * 32;
            if (wave < 2)
                async16(Ap + (size_t)(bm + wave * 16 + lrow) * DCC + k0 + lc8,
                        &As2[cur ^ 1][wave * 512]);
            #pragma unroll
            for (int r = 0; r < 4; ++r)
                async16(Wp + (size_t)((r * 8 + wave) * 16 + lrow) * DCC + k0 + lc8,
                        &Bs[cur ^ 1][(r * 8 + wave) * 512]);
        }
        short8 af[2], bfr[4];
        #pragma unroll
        for (int mi = 0; mi < 2; ++mi)
            af[mi] = *(const short8*)&As2[cur][(mi * 16 + l15) * 32 + lh * 8];
        #pragma unroll
        for (int ni = 0; ni < 4; ++ni)
            bfr[ni] = *(const short8*)&Bs[cur][(wave * 64 + ni * 16 + l15) * 32 + lh * 8];
        #pragma unroll
        for (int mi = 0; mi < 2; ++mi)
            #pragma unroll
            for (int ni = 0; ni < 4; ++ni)
                acc[mi][ni] = __builtin_amdgcn_mfma_f32_16x16x32_bf16(
                    af[mi], bfr[ni], acc[mi][ni], 0, 0, 0);
        __syncthreads();   // drains next-tile vmcnt + this-tile lgkm
    }

    // ---- phase 1: bias + LN1 row stats in MFMA layout ----
    float bv[4], gv[4], bbv[4];
    #pragma unroll
    for (int ni = 0; ni < 4; ++ni) {
        int col = wave * 64 + ni * 16 + l15;
        bv[ni] = bias[col]; gv[ni] = g[col]; bbv[ni] = b[col];
    }

    float ps[2][4], pq[2][4];
    #pragma unroll
    for (int mi = 0; mi < 2; ++mi)
        #pragma unroll
        for (int rr = 0; rr < 4; ++rr) {
            float s = 0.f, q = 0.f;
            #pragma unroll
            for (int ni = 0; ni < 4; ++ni) {
                float v = acc[mi][ni][rr] + bv[ni];
                acc[mi][ni][rr] = v;
                s += v; q += v * v;
            }
            #pragma unroll
            for (int off = 1; off < 16; off <<= 1) {
                s += __shfl_xor(s, off, 64);
                q += __shfl_xor(q, off, 64);
            }
            ps[mi][rr] = s; pq[mi][rr] = q;
        }
    if (l15 == 0) {
        #pragma unroll
        for (int mi = 0; mi < 2; ++mi)
            #pragma unroll
            for (int rr = 0; rr < 4; ++rr) {
                int rl = mi * 16 + lh * 4 + rr;
                red[0][wave][rl] = ps[mi][rr];
                red[1][wave][rl] = pq[mi][rr];
            }
    }
    __syncthreads();

    // comp = LN1 result, staged to LDS (reuse Bs[0]: 32x512 bf16 = 32 KB;
    // K-loop's final reads were from Bs[1], so Bs[0] is dead here)
    unsigned short* compS = &Bs[0][0];
    #pragma unroll
    for (int mi = 0; mi < 2; ++mi)
        #pragma unroll
        for (int rr = 0; rr < 4; ++rr) {
            int rl = mi * 16 + lh * 4 + rr;
            float s = 0.f, q = 0.f;
            #pragma unroll
            for (int w = 0; w < 8; ++w) { s += red[0][w][rl]; q += red[1][w][rl]; }
            float m1 = s * (1.0f / DCC);
            float r1 = rsqrtf(q * (1.0f / DCC) - m1 * m1 + 1e-5f);
            #pragma unroll
            for (int ni = 0; ni < 4; ++ni) {
                int col = wave * 64 + ni * 16 + l15;
                compS[csw(rl, col)] = f2bf((acc[mi][ni][rr] - m1) * r1 * gv[ni] + bbv[ni]);
            }
        }
    __syncthreads();

    // ---- phase 2: row-mapped (wave owns 4 rows, lane owns 8 contiguous cols)
    const int c0 = lane * 8;
    if constexpr (MODE == 0) {
        #pragma unroll
        for (int rr = 0; rr < 4; ++rr) {
            const int rl = wave * 4 + rr;
            const size_t gbase = (size_t)(bm + rl) * DCC + c0;
            short8 cm = *(const short8*)&compS[csw(rl, c0)];
            *(short8*)(outp + gbase) = cm;
        }
    } else {
        float gr[8], br[8], pr[8];
        {
            float4 g0 = *(const float4*)(g + c0),     g1 = *(const float4*)(g + c0 + 4);
            float4 b0 = *(const float4*)(b + c0),     b1 = *(const float4*)(b + c0 + 4);
            float4 p0 = *(const float4*)(logit + c0), p1 = *(const float4*)(logit + c0 + 4);
            float gt[8] = {g0.x,g0.y,g0.z,g0.w,g1.x,g1.y,g1.z,g1.w};
            float bt[8] = {b0.x,b0.y,b0.z,b0.w,b1.x,b1.y,b1.z,b1.w};
            float pt[8] = {p0.x,p0.y,p0.z,p0.w,p1.x,p1.y,p1.z,p1.w};
            #pragma unroll
            for (int j = 0; j < 8; ++j) {
                gr[j] = gt[j]; br[j] = bt[j];
                pr[j] = 1.0f / (1.0f + __expf(-pt[j]));
            }
        }
        #pragma unroll
        for (int rr = 0; rr < 4; ++rr) {
            const int rl = wave * 4 + rr;
            const size_t gbase = (size_t)(bm + rl) * DCC + c0;
            short8 cm = *(const short8*)&compS[csw(rl, c0)];
            short8 ar = *(const short8*)(a_in + gbase);
            short8 tr = *(const short8*)(t_in + gbase);
            short8 lr = *(const short8*)(lat_in + gbase);
            float tv[8], s = 0.f, q = 0.f;
            #pragma unroll
            for (int j = 0; j < 8; ++j) {
                float val = bf2f((unsigned short)ar[j])
                          + 0.5f * (bf2f((unsigned short)cm[j]) - bf2f((unsigned short)tr[j])) * pr[j]
                          + 0.1f * bf2f((unsigned short)lr[j]);
                tv[j] = val; s += val; q += val * val;
            }
            #pragma unroll
            for (int off = 1; off < 64; off <<= 1) {
                s += __shfl_xor(s, off, 64);
                q += __shfl_xor(q, off, 64);
            }
            float m2 = s * (1.0f / DCC);
            float r2 = rsqrtf(q * (1.0f / DCC) - m2 * m2 + 1e-5f);
            short8 o;
            #pragma unroll
            for (int j = 0; j < 8; ++j)
                o[j] = (short)f2bf((tv[j] - m2) * r2 * gr[j] + br[j]);
            *(short8*)(outp + gbase) = o;
        }
    }
}

// ---------------------------------------------------------------------------
extern "C" void kernel_launch(void* const* d_in, const int* in_sizes, int n_in,
                              void* d_out, int out_size, void* d_ws, size_t ws_size,
                              hipStream_t stream)
{
    const float* qwen   = (const float*)d_in[0];
    const float* obs    = (const float*)d_in[1];
    const float* proj_W = (const float*)d_in[2];
    const float* proj_b = (const float*)d_in[3];
    const float* fuse_W = (const float*)d_in[4];
    const float* fuse_b = (const float*)d_in[5];
    const float* up_W   = (const float*)d_in[6];
    const float* up_b   = (const float*)d_in[7];
    const float* lat_W  = (const float*)d_in[8];
    const float* lat_b  = (const float*)d_in[9];
    const float* plogit = (const float*)d_in[10];
    const float* ln_g   = (const float*)d_in[11];
    const float* ln_b   = (const float*)d_in[12];
    const float* down_W = (const float*)d_in[13];
    const float* down_b = (const float*)d_in[14];
    const float* out1_W = (const float*)d_in[15];
    const float* out1_b = (const float*)d_in[16];
    const float* out2_W = (const float*)d_in[17];
    const float* out2_b = (const float*)d_in[18];
    float* out = (float*)d_out;

    // ---- ws layout (ushort): cat | x0 | acts0..3 | weights | obs16
    unsigned short* wsu = (unsigned short*)d_ws;
    unsigned short* catbuf = wsu;                          // 16,777,216
    unsigned short* x0b    = wsu + 16777216;               // 4,194,304
    unsigned short* acts16[4] = {
        wsu + 20971520, wsu + 20971520 + TOKH,
        wsu + 20971520 + 2 * TOKH, wsu + 20971520 + 3 * TOKH };
    unsigned short* w16    = wsu + 37748736;               // 9,437,184
    unsigned short* projW16 = w16;                         // 4,194,304
    unsigned short* fuseW16 = w16 + 4194304;               // 1,048,576
    unsigned short* upW16   = w16 + 5242880;               // 1,048,576
    unsigned short* latW16  = w16 + 6291456;               // 1,048,576
    unsigned short* downW16 = w16 + 7340032;               //   786,432
    unsigned short* out1W16 = w16 + 8126464;               //   262,144
    unsigned short* out2W16 = w16 + 8388608;               // 1,048,576
    unsigned short* obs16   = wsu + 47185920;              // 67,108,864 (134 MB)
    unsigned short* h16     = catbuf;                      // alias (cat dead after fuse)

    // ---- d_out overlays: pred a/b + lat0..3 (6 x 8.4 MB; dead before out2)
    unsigned short* outu = (unsigned short*)d_out;
    unsigned short* pred16a = outu;
    unsigned short* pred16b = outu + TOKH;
    unsigned short* lat16[4] = { outu + 2*TOKH, outu + 3*TOKH, outu + 4*TOKH, outu + 5*TOKH };

    dim3 blk(256);
    dim3 blk512(512);

    // ---- all weight conversions in one launch
    {
        CvtArgs ca;
        ca.src[0] = proj_W; ca.src[1] = fuse_W; ca.src[2] = up_W;
        ca.src[3] = lat_W;  ca.src[4] = down_W; ca.src[5] = out1_W;
        ca.src[6] = out2_W;
        wcvt_kernel<<<dim3(2048), blk, 0, stream>>>(ca, w16);
    }

    // ---- full obs -> bf16 (one launch), then proj z=4 GEMM into cat cols
    {
        int n4 = (4 * NTOK * DMD) / 4;
        cvt_kernel<<<dim3(n4 / 256), blk, 0, stream>>>(obs, obs16, n4);
        GArgs a{};
        for (int o = 0; o < 4; ++o) {
            a.A[o]    = obs16 + (size_t)o * NTOK * DMD;
            a.W[o]    = projW16 + (size_t)o * DCC * DMD;
            a.bias[o] = proj_b + o * DCC;
            a.C[o]    = catbuf + o * DCC;        // ldc = 2048, column offset
        }
        gemm16<false, false><<<dim3(DCC/128, NTOK/128, 4), blk, 0, stream>>>(
            a, DMD, DMD, 0, 4 * DCC, DMD);
    }
    // ---- fuse: x0 = cat @ fuse_W^T + fuse_b  (K=2048)
    {
        GArgs a{};
        a.A[0] = catbuf; a.W[0] = fuseW16; a.bias[0] = fuse_b; a.C[0] = x0b;
        gemm16<false, false><<<dim3(DCC/128, NTOK/128, 1), blk, 0, stream>>>(
            a, 4 * DCC, 4 * DCC, 0, DCC, 4 * DCC);
    }

    dim3 fgrid(NTOK / 32);

    // ---- initial bottom-up pass: fused GEMM+LN
    for (int i = 0; i < 4; ++i) {
        gemm_fused<0><<<fgrid, blk512, 0, stream>>>(
            (i == 0) ? x0b : acts16[i - 1],
            upW16 + (size_t)i * DCC * DCC, up_b + i * DCC,
            ln_g + i * DCC, ln_b + i * DCC,
            nullptr, nullptr, nullptr, nullptr, acts16[i]);
    }

    // ---- settling iterations
    for (int s = 0; s < 5; ++s) {
        // batched independents: pred0, pred1, lat0..lat3 (all from pre-sweep acts)
        {
            GArgs a{};
            a.A[0] = acts16[1]; a.W[0] = downW16 + (size_t)1 * DCC * DCC;
            a.bias[0] = down_b + 1 * DCC; a.C[0] = pred16a;
            a.A[1] = acts16[2]; a.W[1] = downW16 + (size_t)2 * DCC * DCC;
            a.bias[1] = down_b + 2 * DCC; a.C[1] = pred16b;
            for (int i = 0; i < 4; ++i) {
                a.A[2 + i] = acts16[i];
                a.W[2 + i] = latW16 + (size_t)i * DCC * DCC;
                a.bias[2 + i] = lat_b + i * DCC;
                a.C[2 + i] = lat16[i];
            }
            gemm16<false, false><<<dim3(DCC/128, NTOK/128, 6), blk, 0, stream>>>(
                a, DCC, DCC, 0, DCC, DCC);
        }
        // sequential chain: fused up-GEMM + update per layer (in-place on acts)
        for (int i = 0; i < 4; ++i) {
            const unsigned short* tgt =
                (i == 0) ? pred16a : (i == 1) ? pred16b : acts16[i];
            gemm_fused<1><<<fgrid, blk512, 0, stream>>>(
                (i == 0) ? x0b : acts16[i - 1],
                upW16 + (size_t)i * DCC * DCC, up_b + i * DCC,
                ln_g + i * DCC, ln_b + i * DCC,
                acts16[i], tgt, lat16[i], plogit + i * DCC, acts16[i]);
        }
    }

    // ---- head
    {
        GArgs a{};
        a.A[0] = acts16[3]; a.W[0] = out1W16; a.bias[0] = out1_b; a.C[0] = h16;
        gemm16<false, true><<<dim3(DCC/128, NTOK/128, 1), blk, 0, stream>>>(
            a, DCC, DCC, 0, DCC, DCC);
    }
    {
        GArgs a{};
        a.A[0] = h16; a.W[0] = out2W16; a.bias[0] = out2_b;
        a.add[0] = qwen; a.C[0] = out;
        gemm16<true, false><<<dim3(DMD/128, NTOK/128, 1), blk, 0, stream>>>(
            a, DCC, DCC, DMD, DMD, DCC);
    }
}